// Round 5
// baseline (226.426 us; speedup 1.0000x reference)
//
#include <hip/hip_runtime.h>
#include <math.h>

// TokenRouter: LN(x) -> silu(x @ Wd^T) -> @ Wu^T -> top2 softmax
// H=2048, D=64, E=8, NTOK=16384, fp32 in/out.
//
// R13: DRAM-channel-friendly X path (LDS transpose staging).
//  Theory: X row stride 8192B == 0 mod channel interleave, so lane=token
//  loads put a wave's whole burst on ONE HBM channel; a block covers ~8/32
//  channels -> ~25% read efficiency (matches 1.5-2.0 TB/s measured vs
//  6.9 TB/s fills). Burst size (R12) and prefetch depth (R10) were neutral
//  because neither changes the channel distribution.
//  Fix: stage X via LDS. Global loads are 1KB contiguous per wave-inst
//  (64 lanes x 16B of ONE row, 4+ channels, page-sequential). Chunk =
//  [32 tok][256 k] f32, double-buffered, ALIASED onto `red` (only used
//  post-loop) -> LDS stays 78336B, 2 blocks/CU. Blocks walk chunks in
//  rotated order ((c+bid)&7) so the device covers all 8 column windows =
//  all channels concurrently.
//  K ownership re-interleaved: wave s owns k = c*256 + s*32 + [0,32) of
//  chunk c (2 MFMA steps/chunk); prep_kernel stores Wp so (s,t=c*2+j)
//  fetch exactly those k -> router B-frag addressing unchanged.
//  LDS layout [32][260] (16B-aligned rows) + 16B-group swizzle
//  colg ^= (row>>3)&3 -> near-conflict-free b128 reads.
//  Numerics: same k-set per output, regrouped partials -> ~1e-6 on logits.
//  R12 lesson: __launch_bounds__(512,2) (the (512,4) 64-VGPR cap caused
//  every spill). R9 lesson: no full unroll. R4: no runtime-indexed arrays.

#define H     2048
#define DBOT  64
#define NE    8
#define NTB   32              // tokens per block (one 32x32 A tile)
#define SPLIT 8               // waves per block / k-interleave factor
#define KSL   (H / SPLIT)     // 256 k per wave total
#define NST   (KSL / 16)      // 16 MFMA k-steps per wave
#define NCH   8               // chunks of 256 k
#define CH    256             // floats per chunk per row
#define ROWF  260             // padded LDS row stride (floats, 16B aligned)
#define XBN   (NTB * ROWF)    // 8320 floats per chunk buffer
#define RSTT  36              // combine row stride (32 tok + 4 pad)
#define WP_SHORTS (DBOT * H * 2)   // 262144 shorts = 512 KB

typedef short  bf16x8  __attribute__((ext_vector_type(8)));
typedef float  f32x4   __attribute__((ext_vector_type(4)));
typedef float  f32x16  __attribute__((ext_vector_type(16)));

__device__ __forceinline__ unsigned short bf16rne(float x) {
    unsigned u = __float_as_uint(x);
    return (unsigned short)((u + 0x7FFFu + ((u >> 16) & 1u)) >> 16);
}
__device__ __forceinline__ float bf16tof(unsigned short h) {
    return __uint_as_float(((unsigned)h) << 16);
}
// flat short index of the 8-short B-frag group (s,t,tj,hilo,kh,row n)
__device__ __forceinline__ int wp_idx(int s, int t, int tj, int hilo,
                                      int kh, int n) {
    return ((((((s * NST + t) * 2 + tj) * 2 + hilo) * 2 + kh) << 5) + n) << 3;
}

// ---------------- Kernel 1: preconvert W ----------------
// R13 reindex: k0 = c*256 + s*32 + j*16 + kh*8 ; wave s, step t = c*2 + j.
__global__ __launch_bounds__(256) void prep_kernel(
    const float* __restrict__ Wd,     // [DBOT][H]
    const float* __restrict__ gamma,  // [H]
    const float* __restrict__ beta,   // [H]
    unsigned short* __restrict__ Wp,  // [WP_SHORTS]
    float* __restrict__ Bd,           // [DBOT]
    float* __restrict__ Cd)           // [DBOT]
{
    __shared__ float bred[4], cred[4];
    const int d   = blockIdx.x;
    const int tid = threadIdx.x;
    const int k0  = tid * 8;                   // 8 consecutive k, 8-aligned
    const int c   = k0 >> 8;                   // chunk
    const int s   = (k0 >> 5) & 7;             // owning wave within chunk
    const int j   = (k0 >> 4) & 1;             // step within chunk
    const int t   = c * 2 + j;                 // wave-local step index
    const int kh  = (k0 >> 3) & 1;
    const int tj  = d >> 5;
    const int n   = d & 31;

    const float4 w0 = *(const float4*)&Wd[d * H + k0];
    const float4 w1 = *(const float4*)&Wd[d * H + k0 + 4];
    const float4 g0 = *(const float4*)&gamma[k0];
    const float4 g1 = *(const float4*)&gamma[k0 + 4];
    const float4 b0 = *(const float4*)&beta [k0];
    const float4 b1 = *(const float4*)&beta [k0 + 4];

    const float wg0 = w0.x * g0.x, wg1 = w0.y * g0.y;
    const float wg2 = w0.z * g0.z, wg3 = w0.w * g0.w;
    const float wg4 = w1.x * g1.x, wg5 = w1.y * g1.y;
    const float wg6 = w1.z * g1.z, wg7 = w1.w * g1.w;

    float bp = ((wg0 + wg1) + (wg2 + wg3)) + ((wg4 + wg5) + (wg6 + wg7));
    float cp = ((w0.x*b0.x + w0.y*b0.y) + (w0.z*b0.z + w0.w*b0.w))
             + ((w1.x*b1.x + w1.y*b1.y) + (w1.z*b1.z + w1.w*b1.w));

    ushort4 h0, h1, l0, l1;
    h0.x = bf16rne(wg0); h0.y = bf16rne(wg1);
    h0.z = bf16rne(wg2); h0.w = bf16rne(wg3);
    h1.x = bf16rne(wg4); h1.y = bf16rne(wg5);
    h1.z = bf16rne(wg6); h1.w = bf16rne(wg7);
    l0.x = bf16rne(wg0 - bf16tof(h0.x));
    l0.y = bf16rne(wg1 - bf16tof(h0.y));
    l0.z = bf16rne(wg2 - bf16tof(h0.z));
    l0.w = bf16rne(wg3 - bf16tof(h0.w));
    l1.x = bf16rne(wg4 - bf16tof(h1.x));
    l1.y = bf16rne(wg5 - bf16tof(h1.y));
    l1.z = bf16rne(wg6 - bf16tof(h1.z));
    l1.w = bf16rne(wg7 - bf16tof(h1.w));

    const int ih = wp_idx(s, t, tj, 0, kh, n);
    const int il = wp_idx(s, t, tj, 1, kh, n);
    *(ushort4*)&Wp[ih]     = h0;
    *(ushort4*)&Wp[ih + 4] = h1;
    *(ushort4*)&Wp[il]     = l0;
    *(ushort4*)&Wp[il + 4] = l1;

    // block-reduce bp/cp (4 waves)
    #pragma unroll
    for (int m = 1; m < 64; m <<= 1) {
        bp += __shfl_xor(bp, m);
        cp += __shfl_xor(cp, m);
    }
    if ((tid & 63) == 0) { bred[tid >> 6] = bp; cred[tid >> 6] = cp; }
    __syncthreads();
    if (tid == 0) {
        Bd[d] = (bred[0] + bred[1]) + (bred[2] + bred[3]);
        Cd[d] = (cred[0] + cred[1]) + (cred[2] + cred[3]);
    }
}

// ---------------- Kernel 2: main ----------------
__global__ __launch_bounds__(512, 2) void router_kernel(
    const float* __restrict__ X,            // [ntok][H]
    const unsigned short* __restrict__ Wp,  // preconverted W
    const float* __restrict__ Wu,           // [NE][DBOT]
    const float* __restrict__ Bd,
    const float* __restrict__ Cd,
    float* __restrict__ out,                // [ntok][NE]
    const int ntok)
{
    __shared__ float red[SPLIT * DBOT * RSTT];   // 73728 B; ALSO x-chunk bufs
    __shared__ float xsS[SPLIT][NTB], xqS[SPLIT][NTB];
    __shared__ float wuS[NE * DBOT];
    __shared__ float BdS[DBOT], CdS[DBOT];

    const int tid = threadIdx.x;
    const int s   = tid >> 6;        // wave id = k-interleave owner
    const int ln  = tid & 63;
    const int n   = ln & 31;         // A: token row / B: d row in tile
    const int kh  = ln >> 5;         // k-half within 16-k step
    const long tok0 = (long)blockIdx.x * NTB;

    if (tid < 128) ((float4*)wuS)[tid] = ((const float4*)Wu)[tid];
    if (tid < 64)  { BdS[tid] = Bd[tid]; CdS[tid] = Cd[tid]; }

    // chunk buffers alias red (red only used after the loop)
    float* const xb0 = red;
    float* const xb1 = red + XBN;    // 2*8320 = 16640 <= 18432 floats

    const float* Xb = &X[tok0 * (long)H];
    const unsigned short* WpB = &Wp[wp_idx(s, 0, 0, 0, kh, n)];
    const int wstep = wp_idx(0, 1, 0, 0, 0, 0);          // 2048 shorts
    const int oB01  = wp_idx(0, 0, 0, 1, 0, 0);          // hilo stride 512
    const int oB10  = wp_idx(0, 0, 1, 0, 0, 0);          // tj stride 1024

    const int crot = blockIdx.x & 7;     // per-block chunk rotation
    const int dsw  = (n >> 3) & 3;       // read-side 16B-group swizzle
    const float4 z4 = make_float4(0.f, 0.f, 0.f, 0.f);

    // staging: wave s loads rows s, s+8, s+16, s+24; lane ln covers 16B each
    const int r0 = s, r1 = s + 8, r2 = s + 16, r3 = s + 24;
    const int wc0 = ln ^ ((r0 >> 3) & 3);
    const int wc1 = ln ^ ((r1 >> 3) & 3);
    const int wc2 = ln ^ ((r2 >> 3) & 3);
    const int wc3 = ln ^ ((r3 >> 3) & 3);
    const bool ok0 = (tok0 + r0) < ntok;
    const bool ok1 = (tok0 + r1) < ntok;
    const bool ok2 = (tok0 + r2) < ntok;
    const bool ok3 = (tok0 + r3) < ntok;

    f32x16 acc0 = {}, acc1 = {};
    float xs = 0.f, xq = 0.f;

    // ---- prologue: stage chunk crot into xb0 (1KB contiguous per inst)
    {
        const long cb = (long)crot * CH + ln * 4;
        const float4 a = ok0 ? *(const float4*)&Xb[(long)r0 * H + cb] : z4;
        const float4 b = ok1 ? *(const float4*)&Xb[(long)r1 * H + cb] : z4;
        const float4 c = ok2 ? *(const float4*)&Xb[(long)r2 * H + cb] : z4;
        const float4 d = ok3 ? *(const float4*)&Xb[(long)r3 * H + cb] : z4;
        *(float4*)&xb0[r0 * ROWF + wc0 * 4] = a;
        *(float4*)&xb0[r1 * ROWF + wc1 * 4] = b;
        *(float4*)&xb0[r2 * ROWF + wc2 * 4] = c;
        *(float4*)&xb0[r3 * ROWF + wc3 * 4] = d;
        __syncthreads();
    }

    #pragma unroll 2
    for (int c = 0; c < NCH; ++c) {
        const int cc = (c + crot) & 7;               // actual chunk
        float* const cur = (c & 1) ? xb1 : xb0;
        float* const nxt = (c & 1) ? xb0 : xb1;

        // issue next chunk's global loads early (whole compute phase of flight)
        const int cn = (c + 1 < NCH) ? ((c + 1 + crot) & 7) : cc;
        const long cb = (long)cn * CH + ln * 4;
        const float4 sg0 = ok0 ? *(const float4*)&Xb[(long)r0 * H + cb] : z4;
        const float4 sg1 = ok1 ? *(const float4*)&Xb[(long)r1 * H + cb] : z4;
        const float4 sg2 = ok2 ? *(const float4*)&Xb[(long)r2 * H + cb] : z4;
        const float4 sg3 = ok3 ? *(const float4*)&Xb[(long)r3 * H + cb] : z4;

        const int t0 = cc * 2;
        const int t1 = t0 + 1;

        // ---------- step t0: k = cc*256 + s*32 + kh*8 + [0,8) ----------
        {
            const unsigned short* wp0 = &WpB[t0 * wstep];
            const bf16x8 B00 = *(const bf16x8*)&wp0[0];
            const bf16x8 B01 = *(const bf16x8*)&wp0[oB01];
            const bf16x8 B10 = *(const bf16x8*)&wp0[oB10];
            const bf16x8 B11 = *(const bf16x8*)&wp0[oB10 + oB01];

            const int cg = s * 8 + kh * 2;           // 16B-group in chunk row
            const float4 va = *(const float4*)&cur[n * ROWF + ((cg    ) ^ dsw) * 4];
            const float4 vb = *(const float4*)&cur[n * ROWF + ((cg + 1) ^ dsw) * 4];

            xs += ((va.x + va.y) + (va.z + va.w)) + ((vb.x + vb.y) + (vb.z + vb.w));
            xq += ((va.x*va.x + va.y*va.y) + (va.z*va.z + va.w*va.w))
                + ((vb.x*vb.x + vb.y*vb.y) + (vb.z*vb.z + vb.w*vb.w));
            bf16x8 Ah, Al;
            Ah[0] = (short)bf16rne(va.x); Ah[1] = (short)bf16rne(va.y);
            Ah[2] = (short)bf16rne(va.z); Ah[3] = (short)bf16rne(va.w);
            Ah[4] = (short)bf16rne(vb.x); Ah[5] = (short)bf16rne(vb.y);
            Ah[6] = (short)bf16rne(vb.z); Ah[7] = (short)bf16rne(vb.w);
            Al[0] = (short)bf16rne(va.x - bf16tof((unsigned short)Ah[0]));
            Al[1] = (short)bf16rne(va.y - bf16tof((unsigned short)Ah[1]));
            Al[2] = (short)bf16rne(va.z - bf16tof((unsigned short)Ah[2]));
            Al[3] = (short)bf16rne(va.w - bf16tof((unsigned short)Ah[3]));
            Al[4] = (short)bf16rne(vb.x - bf16tof((unsigned short)Ah[4]));
            Al[5] = (short)bf16rne(vb.y - bf16tof((unsigned short)Ah[5]));
            Al[6] = (short)bf16rne(vb.z - bf16tof((unsigned short)Ah[6]));
            Al[7] = (short)bf16rne(vb.w - bf16tof((unsigned short)Ah[7]));

            acc0 = __builtin_amdgcn_mfma_f32_32x32x16_bf16(Ah, B00, acc0, 0, 0, 0);
            acc1 = __builtin_amdgcn_mfma_f32_32x32x16_bf16(Ah, B10, acc1, 0, 0, 0);
            acc0 = __builtin_amdgcn_mfma_f32_32x32x16_bf16(Ah, B01, acc0, 0, 0, 0);
            acc1 = __builtin_amdgcn_mfma_f32_32x32x16_bf16(Ah, B11, acc1, 0, 0, 0);
            acc0 = __builtin_amdgcn_mfma_f32_32x32x16_bf16(Al, B00, acc0, 0, 0, 0);
            acc1 = __builtin_amdgcn_mfma_f32_32x32x16_bf16(Al, B10, acc1, 0, 0, 0);
        }

        // ---------- step t1: k = cc*256 + s*32 + 16 + kh*8 + [0,8) ----------
        {
            const unsigned short* wp1 = &WpB[t1 * wstep];
            const bf16x8 C00 = *(const bf16x8*)&wp1[0];
            const bf16x8 C01 = *(const bf16x8*)&wp1[oB01];
            const bf16x8 C10 = *(const bf16x8*)&wp1[oB10];
            const bf16x8 C11 = *(const bf16x8*)&wp1[oB10 + oB01];

            const int cg = s * 8 + 4 + kh * 2;
            const float4 vc = *(const float4*)&cur[n * ROWF + ((cg    ) ^ dsw) * 4];
            const float4 vd = *(const float4*)&cur[n * ROWF + ((cg + 1) ^ dsw) * 4];

            xs += ((vc.x + vc.y) + (vc.z + vc.w)) + ((vd.x + vd.y) + (vd.z + vd.w));
            xq += ((vc.x*vc.x + vc.y*vc.y) + (vc.z*vc.z + vc.w*vc.w))
                + ((vd.x*vd.x + vd.y*vd.y) + (vd.z*vd.z + vd.w*vd.w));
            bf16x8 Ah, Al;
            Ah[0] = (short)bf16rne(vc.x); Ah[1] = (short)bf16rne(vc.y);
            Ah[2] = (short)bf16rne(vc.z); Ah[3] = (short)bf16rne(vc.w);
            Ah[4] = (short)bf16rne(vd.x); Ah[5] = (short)bf16rne(vd.y);
            Ah[6] = (short)bf16rne(vd.z); Ah[7] = (short)bf16rne(vd.w);
            Al[0] = (short)bf16rne(vc.x - bf16tof((unsigned short)Ah[0]));
            Al[1] = (short)bf16rne(vc.y - bf16tof((unsigned short)Ah[1]));
            Al[2] = (short)bf16rne(vc.z - bf16tof((unsigned short)Ah[2]));
            Al[3] = (short)bf16rne(vc.w - bf16tof((unsigned short)Ah[3]));
            Al[4] = (short)bf16rne(vd.x - bf16tof((unsigned short)Ah[4]));
            Al[5] = (short)bf16rne(vd.y - bf16tof((unsigned short)Ah[5]));
            Al[6] = (short)bf16rne(vd.z - bf16tof((unsigned short)Ah[6]));
            Al[7] = (short)bf16rne(vd.w - bf16tof((unsigned short)Ah[7]));

            acc0 = __builtin_amdgcn_mfma_f32_32x32x16_bf16(Ah, C00, acc0, 0, 0, 0);
            acc1 = __builtin_amdgcn_mfma_f32_32x32x16_bf16(Ah, C10, acc1, 0, 0, 0);
            acc0 = __builtin_amdgcn_mfma_f32_32x32x16_bf16(Ah, C01, acc0, 0, 0, 0);
            acc1 = __builtin_amdgcn_mfma_f32_32x32x16_bf16(Ah, C11, acc1, 0, 0, 0);
            acc0 = __builtin_amdgcn_mfma_f32_32x32x16_bf16(Al, C00, acc0, 0, 0, 0);
            acc1 = __builtin_amdgcn_mfma_f32_32x32x16_bf16(Al, C10, acc1, 0, 0, 0);
        }

        __syncthreads();                 // all reads of cur done
        if (c + 1 < NCH) {
            *(float4*)&nxt[r0 * ROWF + wc0 * 4] = sg0;
            *(float4*)&nxt[r1 * ROWF + wc1 * 4] = sg1;
            *(float4*)&nxt[r2 * ROWF + wc2 * 4] = sg2;
            *(float4*)&nxt[r3 * ROWF + wc3 * 4] = sg3;
            __syncthreads();             // writes visible before next reads
        }
    }

    // ---- stats: fold kh pair, write wave partials
    xs += __shfl_xor(xs, 32);
    xq += __shfl_xor(xq, 32);
    if (ln < 32) { xsS[s][n] = xs; xqS[s][n] = xq; }

    // ---- write per-wave C partials: red[(s*64 + d)*RSTT + token_row]
    // (safe: last barrier above precedes these aliased writes)
    {
        float* rp0 = &red[(s * DBOT + n) * RSTT + 4 * kh];        // tj=0: d=n
        float* rp1 = &red[(s * DBOT + 32 + n) * RSTT + 4 * kh];   // tj=1
        const f32x4 a0 = {acc0[0],  acc0[1],  acc0[2],  acc0[3]};
        const f32x4 a1 = {acc0[4],  acc0[5],  acc0[6],  acc0[7]};
        const f32x4 a2 = {acc0[8],  acc0[9],  acc0[10], acc0[11]};
        const f32x4 a3 = {acc0[12], acc0[13], acc0[14], acc0[15]};
        *(f32x4*)&rp0[0]  = a0;
        *(f32x4*)&rp0[8]  = a1;
        *(f32x4*)&rp0[16] = a2;
        *(f32x4*)&rp0[24] = a3;
        const f32x4 b0 = {acc1[0],  acc1[1],  acc1[2],  acc1[3]};
        const f32x4 b1 = {acc1[4],  acc1[5],  acc1[6],  acc1[7]};
        const f32x4 b2 = {acc1[8],  acc1[9],  acc1[10], acc1[11]};
        const f32x4 b3 = {acc1[12], acc1[13], acc1[14], acc1[15]};
        *(f32x4*)&rp1[0]  = b0;
        *(f32x4*)&rp1[8]  = b1;
        *(f32x4*)&rp1[16] = b2;
        *(f32x4*)&rp1[24] = b3;
    }
    __syncthreads();

    // ---- epilogue: token = tid>>4; 16 threads/token; d = cq + 16*i
    {
        const int tok = tid >> 4;
        const int cq  = tid & 15;
        const float invH = 1.0f / (float)H;
        const float rsum = ((xsS[0][tok] + xsS[1][tok]) + (xsS[2][tok] + xsS[3][tok]))
                         + ((xsS[4][tok] + xsS[5][tok]) + (xsS[6][tok] + xsS[7][tok]));
        const float rsq  = ((xqS[0][tok] + xqS[1][tok]) + (xqS[2][tok] + xqS[3][tok]))
                         + ((xqS[4][tok] + xqS[5][tok]) + (xqS[6][tok] + xqS[7][tok]));
        const float mu   = rsum * invH;
        const float var  = rsq * invH - mu * mu;
        const float rstd = 1.0f / sqrtf(var + 1e-5f);

        float lg[NE];
        #pragma unroll
        for (int e = 0; e < NE; ++e) lg[e] = 0.f;
        #pragma unroll
        for (int i = 0; i < 4; ++i) {
            const int d = cq + 16 * i;
            const float A = (((red[(0*DBOT + d)*RSTT + tok] + red[(1*DBOT + d)*RSTT + tok])
                            + (red[(2*DBOT + d)*RSTT + tok] + red[(3*DBOT + d)*RSTT + tok]))
                           + ((red[(4*DBOT + d)*RSTT + tok] + red[(5*DBOT + d)*RSTT + tok])
                            + (red[(6*DBOT + d)*RSTT + tok] + red[(7*DBOT + d)*RSTT + tok])));
            const float t = rstd * (A - mu * BdS[d]) + CdS[d];
            const float z = t / (1.0f + expf(-t));
            #pragma unroll
            for (int e = 0; e < NE; ++e) lg[e] += z * wuS[e * DBOT + d];
        }
        #pragma unroll
        for (int e = 0; e < NE; ++e) {
            lg[e] += __shfl_xor(lg[e], 1);
            lg[e] += __shfl_xor(lg[e], 2);
            lg[e] += __shfl_xor(lg[e], 4);
            lg[e] += __shfl_xor(lg[e], 8);
        }

        if (cq == 0 && tok0 + tok < ntok) {
            // top-2; strict > keeps lowest index on ties (matches lax.top_k)
            float v1 = -INFINITY, v2 = -INFINITY;
            int i1 = -1, i2 = -1;
            #pragma unroll
            for (int e = 0; e < NE; ++e) {
                const float v = lg[e];
                if (v > v1)      { v2 = v1; i2 = i1; v1 = v; i1 = e; }
                else if (v > v2) { v2 = v;  i2 = e; }
            }
            const float e2  = expf(v2 - v1);
            const float inv = 1.0f / (1.0f + e2);
            float o[NE];
            #pragma unroll
            for (int e = 0; e < NE; ++e)
                o[e] = (e == i1) ? inv : ((e == i2) ? e2 * inv : 0.0f);
            float4* op = (float4*)&out[(tok0 + tok) * NE];
            op[0] = make_float4(o[0], o[1], o[2], o[3]);
            op[1] = make_float4(o[4], o[5], o[6], o[7]);
        }
    }
}

extern "C" void kernel_launch(void* const* d_in, const int* in_sizes, int n_in,
                              void* d_out, int out_size, void* d_ws, size_t ws_size,
                              hipStream_t stream) {
    const float* X     = (const float*)d_in[0];
    const float* Wd    = (const float*)d_in[1];
    const float* Wu    = (const float*)d_in[2];
    const float* gamma = (const float*)d_in[3];
    const float* beta  = (const float*)d_in[4];
    float* out = (float*)d_out;

    unsigned short* Wp = (unsigned short*)d_ws;                 // 512 KB
    float* Bd = (float*)((char*)d_ws + WP_SHORTS * sizeof(short));
    float* Cd = Bd + DBOT;

    const int ntok = in_sizes[0] / H;              // 16384
    const int nblk = (ntok + NTB - 1) / NTB;       // 512

    hipLaunchKernelGGL(prep_kernel, dim3(DBOT), dim3(256), 0, stream,
                       Wd, gamma, beta, Wp, Bd, Cd);
    hipLaunchKernelGGL(router_kernel, dim3(nblk), dim3(512), 0, stream,
                       X, Wp, Wu, Bd, Cd, out, ntok);
}

// Round 6
// 217.780 us; speedup vs baseline: 1.0397x; 1.0397x over previous
//
#include <hip/hip_runtime.h>
#include <math.h>

// TokenRouter: LN(x) -> silu(x @ Wd^T) -> @ Wu^T -> top2 softmax
// H=2048, D=64, E=8, NTOK=16384, fp32 in/out.
//
// R14: halve B-side (Wp) traffic via NTB=64 / 1024-thread blocks.
//  History: X-side levers all dead (R10 depth-2 neutral; R12 128B bursts
//  neutral; R13 fully-coalesced LDS staging SLOWER at 945 GB/s HBM with
//  FETCH only 70MB -> X partially LLC-resident, never BW-bound).
//  Remaining model: router time tracks total VMEM traffic/lines, and Wp
//  re-reads are the bigger half: 512 blocks x 512KB = 256MB vs X 134MB.
//  Fix: 256 blocks x 64 tokens. 16 waves = 2 token-tiles(g) x 8 K-slices(s).
//  Wp traffic 256->128MB; twin waves (g=0/1, same s) hit the same Wp lines
//  in L1. Per-wave inner loop byte-identical to R8 (same k-split, same
//  summation order -> absmax 0.0). prep = R8 version (R13 reindex reverted).
//  LDS: red[2][8][64][34] (RSTT=34: b128 write aliasing 2-way = free) +
//  stats = 146KB -> 1 block/CU, still 4 waves/SIMD.
//  R12 lesson: __launch_bounds__ 2nd arg acts like blocks/CU here;
//  (512,4) forced a 64-VGPR cap (spills in R9/R11). (1024,2) -> cap 64,
//  which the R8 loop provably fits (R8/R10 ran 64 VGPR, no spill).
//  R9 lesson: #pragma unroll 2 only. R4: no runtime-indexed reg arrays.

#define H     2048
#define DBOT  64
#define NE    8
#define NTB   64              // tokens per block (two 32x32 A tiles)
#define SPLIT 8               // K-split across waves
#define KSL   (H / SPLIT)     // 256 k per wave
#define NST   (KSL / 16)      // 16 MFMA k-steps per wave
#define RSTT  34              // combine row stride (32 tok + 2 pad)
#define WP_SHORTS (DBOT * H * 2)   // 262144 shorts = 512 KB

typedef short  bf16x8  __attribute__((ext_vector_type(8)));
typedef float  f32x4   __attribute__((ext_vector_type(4)));
typedef float  f32x16  __attribute__((ext_vector_type(16)));

__device__ __forceinline__ unsigned short bf16rne(float x) {
    unsigned u = __float_as_uint(x);
    return (unsigned short)((u + 0x7FFFu + ((u >> 16) & 1u)) >> 16);
}
__device__ __forceinline__ float bf16tof(unsigned short h) {
    return __uint_as_float(((unsigned)h) << 16);
}
// flat short index of the 8-short B-frag group (s,t,tj,hilo,kh,row n)
__device__ __forceinline__ int wp_idx(int s, int t, int tj, int hilo,
                                      int kh, int n) {
    return ((((((s * NST + t) * 2 + tj) * 2 + hilo) * 2 + kh) << 5) + n) << 3;
}

// ---------------- Kernel 1: preconvert W (R8 version) ----------------
__global__ __launch_bounds__(256) void prep_kernel(
    const float* __restrict__ Wd,     // [DBOT][H]
    const float* __restrict__ gamma,  // [H]
    const float* __restrict__ beta,   // [H]
    unsigned short* __restrict__ Wp,  // [WP_SHORTS]
    float* __restrict__ Bd,           // [DBOT]
    float* __restrict__ Cd)           // [DBOT]
{
    __shared__ float bred[4], cred[4];
    const int d   = blockIdx.x;
    const int tid = threadIdx.x;
    const int k0  = tid * 8;                   // 8 consecutive k, 8-aligned
    const int s   = k0 >> 8;
    const int t   = (k0 >> 4) & 15;
    const int kh  = (k0 >> 3) & 1;
    const int tj  = d >> 5;
    const int n   = d & 31;

    const float4 w0 = *(const float4*)&Wd[d * H + k0];
    const float4 w1 = *(const float4*)&Wd[d * H + k0 + 4];
    const float4 g0 = *(const float4*)&gamma[k0];
    const float4 g1 = *(const float4*)&gamma[k0 + 4];
    const float4 b0 = *(const float4*)&beta [k0];
    const float4 b1 = *(const float4*)&beta [k0 + 4];

    const float wg0 = w0.x * g0.x, wg1 = w0.y * g0.y;
    const float wg2 = w0.z * g0.z, wg3 = w0.w * g0.w;
    const float wg4 = w1.x * g1.x, wg5 = w1.y * g1.y;
    const float wg6 = w1.z * g1.z, wg7 = w1.w * g1.w;

    float bp = ((wg0 + wg1) + (wg2 + wg3)) + ((wg4 + wg5) + (wg6 + wg7));
    float cp = ((w0.x*b0.x + w0.y*b0.y) + (w0.z*b0.z + w0.w*b0.w))
             + ((w1.x*b1.x + w1.y*b1.y) + (w1.z*b1.z + w1.w*b1.w));

    ushort4 h0, h1, l0, l1;
    h0.x = bf16rne(wg0); h0.y = bf16rne(wg1);
    h0.z = bf16rne(wg2); h0.w = bf16rne(wg3);
    h1.x = bf16rne(wg4); h1.y = bf16rne(wg5);
    h1.z = bf16rne(wg6); h1.w = bf16rne(wg7);
    l0.x = bf16rne(wg0 - bf16tof(h0.x));
    l0.y = bf16rne(wg1 - bf16tof(h0.y));
    l0.z = bf16rne(wg2 - bf16tof(h0.z));
    l0.w = bf16rne(wg3 - bf16tof(h0.w));
    l1.x = bf16rne(wg4 - bf16tof(h1.x));
    l1.y = bf16rne(wg5 - bf16tof(h1.y));
    l1.z = bf16rne(wg6 - bf16tof(h1.z));
    l1.w = bf16rne(wg7 - bf16tof(h1.w));

    const int ih = wp_idx(s, t, tj, 0, kh, n);
    const int il = wp_idx(s, t, tj, 1, kh, n);
    *(ushort4*)&Wp[ih]     = h0;
    *(ushort4*)&Wp[ih + 4] = h1;
    *(ushort4*)&Wp[il]     = l0;
    *(ushort4*)&Wp[il + 4] = l1;

    // block-reduce bp/cp (4 waves)
    #pragma unroll
    for (int m = 1; m < 64; m <<= 1) {
        bp += __shfl_xor(bp, m);
        cp += __shfl_xor(cp, m);
    }
    if ((tid & 63) == 0) { bred[tid >> 6] = bp; cred[tid >> 6] = cp; }
    __syncthreads();
    if (tid == 0) {
        Bd[d] = (bred[0] + bred[1]) + (bred[2] + bred[3]);
        Cd[d] = (cred[0] + cred[1]) + (cred[2] + cred[3]);
    }
}

// ---------------- Kernel 2: main ----------------
__global__ __launch_bounds__(1024, 2) void router_kernel(
    const float* __restrict__ X,            // [ntok][H]
    const unsigned short* __restrict__ Wp,  // preconverted W
    const float* __restrict__ Wu,           // [NE][DBOT]
    const float* __restrict__ Bd,
    const float* __restrict__ Cd,
    float* __restrict__ out,                // [ntok][NE]
    const int ntok)
{
    __shared__ float red[2 * SPLIT * DBOT * RSTT];   // 139264 B
    __shared__ float xsS[2][SPLIT][32], xqS[2][SPLIT][32];
    __shared__ float wuS[NE * DBOT];
    __shared__ float BdS[DBOT], CdS[DBOT];

    const int tid = threadIdx.x;
    const int w   = tid >> 6;        // wave 0..15
    const int g   = w >> 3;          // token-tile half (0: rows 0-31, 1: 32-63)
    const int s   = w & 7;           // K-slice owner within the tile
    const int ln  = tid & 63;
    const int n   = ln & 31;         // A: token row in tile / B: d row
    const int kh  = ln >> 5;         // k-half within 16-k step
    const long tok0 = (long)blockIdx.x * NTB;

    if (tid < 128) ((float4*)wuS)[tid] = ((const float4*)Wu)[tid];
    if (tid < 64)  { BdS[tid] = Bd[tid]; CdS[tid] = Cd[tid]; }

    const long row = tok0 + g * 32 + n;
    const bool xok = row < ntok;
    const float* Xr = &X[row * (long)H + s * KSL + kh * 8];
    const unsigned short* WpB = &Wp[wp_idx(s, 0, 0, 0, kh, n)];
    const int wstep = wp_idx(0, 1, 0, 0, 0, 0);          // 2048 shorts
    const int oB01  = wp_idx(0, 0, 0, 1, 0, 0);          // hilo stride 512
    const int oB10  = wp_idx(0, 0, 1, 0, 0, 0);          // tj stride 1024

    f32x16 acc0 = {}, acc1 = {};
    float xs = 0.f, xq = 0.f;

    const float4 z4 = make_float4(0.f, 0.f, 0.f, 0.f);
    float4 xa = xok ? *(const float4*)&Xr[0] : z4;
    float4 xb = xok ? *(const float4*)&Xr[4] : z4;
    bf16x8 B00 = *(const bf16x8*)&WpB[0];
    bf16x8 B01 = *(const bf16x8*)&WpB[oB01];
    bf16x8 B10 = *(const bf16x8*)&WpB[oB10];
    bf16x8 B11 = *(const bf16x8*)&WpB[oB10 + oB01];

    #pragma unroll 2
    for (int t = 0; t < NST; ++t) {
        // prefetch t+1
        float4 nxa = z4, nxb = z4;
        bf16x8 nB00 = {}, nB01 = {}, nB10 = {}, nB11 = {};
        if (t + 1 < NST) {
            if (xok) {
                nxa = *(const float4*)&Xr[(t + 1) * 16];
                nxb = *(const float4*)&Xr[(t + 1) * 16 + 4];
            }
            const unsigned short* wp = &WpB[(t + 1) * wstep];
            nB00 = *(const bf16x8*)&wp[0];
            nB01 = *(const bf16x8*)&wp[oB01];
            nB10 = *(const bf16x8*)&wp[oB10];
            nB11 = *(const bf16x8*)&wp[oB10 + oB01];
        }

        // stats + hi/lo convert of current X (8 values)
        xs += ((xa.x + xa.y) + (xa.z + xa.w)) + ((xb.x + xb.y) + (xb.z + xb.w));
        xq += ((xa.x*xa.x + xa.y*xa.y) + (xa.z*xa.z + xa.w*xa.w))
            + ((xb.x*xb.x + xb.y*xb.y) + (xb.z*xb.z + xb.w*xb.w));
        bf16x8 Ah, Al;
        Ah[0] = (short)bf16rne(xa.x); Ah[1] = (short)bf16rne(xa.y);
        Ah[2] = (short)bf16rne(xa.z); Ah[3] = (short)bf16rne(xa.w);
        Ah[4] = (short)bf16rne(xb.x); Ah[5] = (short)bf16rne(xb.y);
        Ah[6] = (short)bf16rne(xb.z); Ah[7] = (short)bf16rne(xb.w);
        Al[0] = (short)bf16rne(xa.x - bf16tof((unsigned short)Ah[0]));
        Al[1] = (short)bf16rne(xa.y - bf16tof((unsigned short)Ah[1]));
        Al[2] = (short)bf16rne(xa.z - bf16tof((unsigned short)Ah[2]));
        Al[3] = (short)bf16rne(xa.w - bf16tof((unsigned short)Ah[3]));
        Al[4] = (short)bf16rne(xb.x - bf16tof((unsigned short)Ah[4]));
        Al[5] = (short)bf16rne(xb.y - bf16tof((unsigned short)Ah[5]));
        Al[6] = (short)bf16rne(xb.z - bf16tof((unsigned short)Ah[6]));
        Al[7] = (short)bf16rne(xb.w - bf16tof((unsigned short)Ah[7]));

        acc0 = __builtin_amdgcn_mfma_f32_32x32x16_bf16(Ah, B00, acc0, 0, 0, 0);
        acc1 = __builtin_amdgcn_mfma_f32_32x32x16_bf16(Ah, B10, acc1, 0, 0, 0);
        acc0 = __builtin_amdgcn_mfma_f32_32x32x16_bf16(Ah, B01, acc0, 0, 0, 0);
        acc1 = __builtin_amdgcn_mfma_f32_32x32x16_bf16(Ah, B11, acc1, 0, 0, 0);
        acc0 = __builtin_amdgcn_mfma_f32_32x32x16_bf16(Al, B00, acc0, 0, 0, 0);
        acc1 = __builtin_amdgcn_mfma_f32_32x32x16_bf16(Al, B10, acc1, 0, 0, 0);

        xa = nxa; xb = nxb;
        B00 = nB00; B01 = nB01; B10 = nB10; B11 = nB11;
    }

    // ---- stats: fold kh pair, write wave partials
    xs += __shfl_xor(xs, 32);
    xq += __shfl_xor(xq, 32);
    if (ln < 32) { xsS[g][s][n] = xs; xqS[g][s][n] = xq; }

    // ---- write per-wave C partials: redg[(s*64 + d)*RSTT + token_row]
    {
        float* redg = red + g * (SPLIT * DBOT * RSTT);
        float* rp0 = &redg[(s * DBOT + n) * RSTT + 4 * kh];        // tj=0: d=n
        float* rp1 = &redg[(s * DBOT + 32 + n) * RSTT + 4 * kh];   // tj=1
        const f32x4 a0 = {acc0[0],  acc0[1],  acc0[2],  acc0[3]};
        const f32x4 a1 = {acc0[4],  acc0[5],  acc0[6],  acc0[7]};
        const f32x4 a2 = {acc0[8],  acc0[9],  acc0[10], acc0[11]};
        const f32x4 a3 = {acc0[12], acc0[13], acc0[14], acc0[15]};
        *(f32x4*)&rp0[0]  = a0;
        *(f32x4*)&rp0[8]  = a1;
        *(f32x4*)&rp0[16] = a2;
        *(f32x4*)&rp0[24] = a3;
        const f32x4 b0 = {acc1[0],  acc1[1],  acc1[2],  acc1[3]};
        const f32x4 b1 = {acc1[4],  acc1[5],  acc1[6],  acc1[7]};
        const f32x4 b2 = {acc1[8],  acc1[9],  acc1[10], acc1[11]};
        const f32x4 b3 = {acc1[12], acc1[13], acc1[14], acc1[15]};
        *(f32x4*)&rp1[0]  = b0;
        *(f32x4*)&rp1[8]  = b1;
        *(f32x4*)&rp1[16] = b2;
        *(f32x4*)&rp1[24] = b3;
    }
    __syncthreads();

    // ---- epilogue: token = tid>>4 (0..63); 16 threads/token; d = cq + 16*i
    {
        const int tok  = tid >> 4;
        const int cq   = tid & 15;
        const int g2   = tok >> 5;
        const int tokl = tok & 31;
        const float* redg = red + g2 * (SPLIT * DBOT * RSTT);
        const float invH = 1.0f / (float)H;
        const float rsum = ((xsS[g2][0][tokl] + xsS[g2][1][tokl])
                          + (xsS[g2][2][tokl] + xsS[g2][3][tokl]))
                         + ((xsS[g2][4][tokl] + xsS[g2][5][tokl])
                          + (xsS[g2][6][tokl] + xsS[g2][7][tokl]));
        const float rsq  = ((xqS[g2][0][tokl] + xqS[g2][1][tokl])
                          + (xqS[g2][2][tokl] + xqS[g2][3][tokl]))
                         + ((xqS[g2][4][tokl] + xqS[g2][5][tokl])
                          + (xqS[g2][6][tokl] + xqS[g2][7][tokl]));
        const float mu   = rsum * invH;
        const float var  = rsq * invH - mu * mu;
        const float rstd = 1.0f / sqrtf(var + 1e-5f);

        float lg[NE];
        #pragma unroll
        for (int e = 0; e < NE; ++e) lg[e] = 0.f;
        #pragma unroll
        for (int i = 0; i < 4; ++i) {
            const int d = cq + 16 * i;
            const float A = (((redg[(0*DBOT + d)*RSTT + tokl] + redg[(1*DBOT + d)*RSTT + tokl])
                            + (redg[(2*DBOT + d)*RSTT + tokl] + redg[(3*DBOT + d)*RSTT + tokl]))
                           + ((redg[(4*DBOT + d)*RSTT + tokl] + redg[(5*DBOT + d)*RSTT + tokl])
                            + (redg[(6*DBOT + d)*RSTT + tokl] + redg[(7*DBOT + d)*RSTT + tokl])));
            const float t = rstd * (A - mu * BdS[d]) + CdS[d];
            const float z = t / (1.0f + expf(-t));
            #pragma unroll
            for (int e = 0; e < NE; ++e) lg[e] += z * wuS[e * DBOT + d];
        }
        #pragma unroll
        for (int e = 0; e < NE; ++e) {
            lg[e] += __shfl_xor(lg[e], 1);
            lg[e] += __shfl_xor(lg[e], 2);
            lg[e] += __shfl_xor(lg[e], 4);
            lg[e] += __shfl_xor(lg[e], 8);
        }

        if (cq == 0 && tok0 + tok < ntok) {
            // top-2; strict > keeps lowest index on ties (matches lax.top_k)
            float v1 = -INFINITY, v2 = -INFINITY;
            int i1 = -1, i2 = -1;
            #pragma unroll
            for (int e = 0; e < NE; ++e) {
                const float v = lg[e];
                if (v > v1)      { v2 = v1; i2 = i1; v1 = v; i1 = e; }
                else if (v > v2) { v2 = v;  i2 = e; }
            }
            const float e2  = expf(v2 - v1);
            const float inv = 1.0f / (1.0f + e2);
            float o[NE];
            #pragma unroll
            for (int e = 0; e < NE; ++e)
                o[e] = (e == i1) ? inv : ((e == i2) ? e2 * inv : 0.0f);
            float4* op = (float4*)&out[(tok0 + tok) * NE];
            op[0] = make_float4(o[0], o[1], o[2], o[3]);
            op[1] = make_float4(o[4], o[5], o[6], o[7]);
        }
    }
}

extern "C" void kernel_launch(void* const* d_in, const int* in_sizes, int n_in,
                              void* d_out, int out_size, void* d_ws, size_t ws_size,
                              hipStream_t stream) {
    const float* X     = (const float*)d_in[0];
    const float* Wd    = (const float*)d_in[1];
    const float* Wu    = (const float*)d_in[2];
    const float* gamma = (const float*)d_in[3];
    const float* beta  = (const float*)d_in[4];
    float* out = (float*)d_out;

    unsigned short* Wp = (unsigned short*)d_ws;                 // 512 KB
    float* Bd = (float*)((char*)d_ws + WP_SHORTS * sizeof(short));
    float* Cd = Bd + DBOT;

    const int ntok = in_sizes[0] / H;              // 16384
    const int nblk = (ntok + NTB - 1) / NTB;       // 256

    hipLaunchKernelGGL(prep_kernel, dim3(DBOT), dim3(256), 0, stream,
                       Wd, gamma, beta, Wp, Bd, Cd);
    hipLaunchKernelGGL(router_kernel, dim3(nblk), dim3(1024), 0, stream,
                       X, Wp, Wu, Bd, Cd, out, ntok);
}

// Round 7
// 212.989 us; speedup vs baseline: 1.0631x; 1.0225x over previous
//
#include <hip/hip_runtime.h>
#include <math.h>

// TokenRouter: LN(x) -> silu(x @ Wd^T) -> @ Wu^T -> top2 softmax
// H=2048, D=64, E=8, NTOK=16384, fp32 in/out.
//
// R15: R8 structure + B-fragment depth-2 prefetch (single variable).
//  Dead theories (all neutral/worse): X prefetch depth (R10), X burst size
//  (R12), X channel coalescing via LDS staging (R13), B byte volume (R14).
//  Live theory: per-step stall ~2800cyc vs ~560 issue+~1024 L1-line cyc;
//  in ALL prior kernels B frags had depth-1 flight (pre-MFMA wait drains
//  to vmcnt(6), giving B(t) one ~560cyc window vs 400-900cyc loaded L2/LLC
//  latency). This is the only untested prefetch-matrix cell.
//  Change: per step issue X(t+1) FIRST, then B(t+2) into a 3rd B set.
//  Wait on X(t) leaves [B(t+1), X(t+1), B(t+2)] outstanding (vmcnt(10));
//  B(t) gets ~2 step-windows of flight. +16 VGPR (~96 live).
//  R12 lesson: __launch_bounds__(512,2) -- the (512,4) 64-VGPR cap caused
//  every spill (R9/R11). LDS 78336B keeps 2 blocks/CU regardless.
//  k order / summation order / Wp layout byte-identical to R8 -> absmax 0.
//  R9 lesson: #pragma unroll 2 only; clamped edge addresses, branchless.
//  R4 lesson: register arrays indexed only by unrolled constants.

#define H     2048
#define DBOT  64
#define NE    8
#define NTB   32              // tokens per block (one 32x32 A tile)
#define SPLIT 8               // K-split across waves
#define KSL   (H / SPLIT)     // 256 k per wave
#define NST   (KSL / 16)      // 16 MFMA k-steps per wave
#define RSTT  36              // combine row stride (32 tok + 4 pad)
#define WP_SHORTS (DBOT * H * 2)   // 262144 shorts = 512 KB

typedef short  bf16x8  __attribute__((ext_vector_type(8)));
typedef float  f32x4   __attribute__((ext_vector_type(4)));
typedef float  f32x16  __attribute__((ext_vector_type(16)));

__device__ __forceinline__ unsigned short bf16rne(float x) {
    unsigned u = __float_as_uint(x);
    return (unsigned short)((u + 0x7FFFu + ((u >> 16) & 1u)) >> 16);
}
__device__ __forceinline__ float bf16tof(unsigned short h) {
    return __uint_as_float(((unsigned)h) << 16);
}
// flat short index of the 8-short B-frag group (s,t,tj,hilo,kh,row n)
__device__ __forceinline__ int wp_idx(int s, int t, int tj, int hilo,
                                      int kh, int n) {
    return ((((((s * NST + t) * 2 + tj) * 2 + hilo) * 2 + kh) << 5) + n) << 3;
}

// ---------------- Kernel 1: preconvert W (R8 version) ----------------
__global__ __launch_bounds__(256) void prep_kernel(
    const float* __restrict__ Wd,     // [DBOT][H]
    const float* __restrict__ gamma,  // [H]
    const float* __restrict__ beta,   // [H]
    unsigned short* __restrict__ Wp,  // [WP_SHORTS]
    float* __restrict__ Bd,           // [DBOT]
    float* __restrict__ Cd)           // [DBOT]
{
    __shared__ float bred[4], cred[4];
    const int d   = blockIdx.x;
    const int tid = threadIdx.x;
    const int k0  = tid * 8;                   // 8 consecutive k, 8-aligned
    const int s   = k0 >> 8;
    const int t   = (k0 >> 4) & 15;
    const int kh  = (k0 >> 3) & 1;
    const int tj  = d >> 5;
    const int n   = d & 31;

    const float4 w0 = *(const float4*)&Wd[d * H + k0];
    const float4 w1 = *(const float4*)&Wd[d * H + k0 + 4];
    const float4 g0 = *(const float4*)&gamma[k0];
    const float4 g1 = *(const float4*)&gamma[k0 + 4];
    const float4 b0 = *(const float4*)&beta [k0];
    const float4 b1 = *(const float4*)&beta [k0 + 4];

    const float wg0 = w0.x * g0.x, wg1 = w0.y * g0.y;
    const float wg2 = w0.z * g0.z, wg3 = w0.w * g0.w;
    const float wg4 = w1.x * g1.x, wg5 = w1.y * g1.y;
    const float wg6 = w1.z * g1.z, wg7 = w1.w * g1.w;

    float bp = ((wg0 + wg1) + (wg2 + wg3)) + ((wg4 + wg5) + (wg6 + wg7));
    float cp = ((w0.x*b0.x + w0.y*b0.y) + (w0.z*b0.z + w0.w*b0.w))
             + ((w1.x*b1.x + w1.y*b1.y) + (w1.z*b1.z + w1.w*b1.w));

    ushort4 h0, h1, l0, l1;
    h0.x = bf16rne(wg0); h0.y = bf16rne(wg1);
    h0.z = bf16rne(wg2); h0.w = bf16rne(wg3);
    h1.x = bf16rne(wg4); h1.y = bf16rne(wg5);
    h1.z = bf16rne(wg6); h1.w = bf16rne(wg7);
    l0.x = bf16rne(wg0 - bf16tof(h0.x));
    l0.y = bf16rne(wg1 - bf16tof(h0.y));
    l0.z = bf16rne(wg2 - bf16tof(h0.z));
    l0.w = bf16rne(wg3 - bf16tof(h0.w));
    l1.x = bf16rne(wg4 - bf16tof(h1.x));
    l1.y = bf16rne(wg5 - bf16tof(h1.y));
    l1.z = bf16rne(wg6 - bf16tof(h1.z));
    l1.w = bf16rne(wg7 - bf16tof(h1.w));

    const int ih = wp_idx(s, t, tj, 0, kh, n);
    const int il = wp_idx(s, t, tj, 1, kh, n);
    *(ushort4*)&Wp[ih]     = h0;
    *(ushort4*)&Wp[ih + 4] = h1;
    *(ushort4*)&Wp[il]     = l0;
    *(ushort4*)&Wp[il + 4] = l1;

    // block-reduce bp/cp (4 waves)
    #pragma unroll
    for (int m = 1; m < 64; m <<= 1) {
        bp += __shfl_xor(bp, m);
        cp += __shfl_xor(cp, m);
    }
    if ((tid & 63) == 0) { bred[tid >> 6] = bp; cred[tid >> 6] = cp; }
    __syncthreads();
    if (tid == 0) {
        Bd[d] = (bred[0] + bred[1]) + (bred[2] + bred[3]);
        Cd[d] = (cred[0] + cred[1]) + (cred[2] + cred[3]);
    }
}

// ---------------- Kernel 2: main ----------------
__global__ __launch_bounds__(512, 2) void router_kernel(
    const float* __restrict__ X,            // [ntok][H]
    const unsigned short* __restrict__ Wp,  // preconverted W
    const float* __restrict__ Wu,           // [NE][DBOT]
    const float* __restrict__ Bd,
    const float* __restrict__ Cd,
    float* __restrict__ out,                // [ntok][NE]
    const int ntok)
{
    __shared__ float red[SPLIT * DBOT * RSTT];   // 73728 B
    __shared__ float xsS[SPLIT][NTB], xqS[SPLIT][NTB];
    __shared__ float wuS[NE * DBOT];
    __shared__ float BdS[DBOT], CdS[DBOT];

    const int tid = threadIdx.x;
    const int s   = tid >> 6;        // wave = K-slice owner
    const int ln  = tid & 63;
    const int n   = ln & 31;         // A: token row / B: d row in tile
    const int kh  = ln >> 5;         // k-half within 16-k step
    const long tok0 = (long)blockIdx.x * NTB;

    if (tid < 128) ((float4*)wuS)[tid] = ((const float4*)Wu)[tid];
    if (tid < 64)  { BdS[tid] = Bd[tid]; CdS[tid] = Cd[tid]; }

    const bool xok = (tok0 + n) < ntok;
    const float* Xr = &X[(tok0 + n) * (long)H + s * KSL + kh * 8];
    const unsigned short* WpB = &Wp[wp_idx(s, 0, 0, 0, kh, n)];
    const int wstep = wp_idx(0, 1, 0, 0, 0, 0);          // 2048 shorts
    const int oB01  = wp_idx(0, 0, 0, 1, 0, 0);          // hilo stride 512
    const int oB10  = wp_idx(0, 0, 1, 0, 0, 0);          // tj stride 1024

    f32x16 acc0 = {}, acc1 = {};
    float xs = 0.f, xq = 0.f;

    const float4 z4 = make_float4(0.f, 0.f, 0.f, 0.f);
    // Prologue: X(0), B(0), B(1). B pipeline: A=B(t), C=B(t+1), D=B(t+2).
    float4 xa = xok ? *(const float4*)&Xr[0] : z4;
    float4 xb = xok ? *(const float4*)&Xr[4] : z4;
    bf16x8 A00 = *(const bf16x8*)&WpB[0];
    bf16x8 A01 = *(const bf16x8*)&WpB[oB01];
    bf16x8 A10 = *(const bf16x8*)&WpB[oB10];
    bf16x8 A11 = *(const bf16x8*)&WpB[oB10 + oB01];
    const unsigned short* wp1 = &WpB[wstep];
    bf16x8 C00 = *(const bf16x8*)&wp1[0];
    bf16x8 C01 = *(const bf16x8*)&wp1[oB01];
    bf16x8 C10 = *(const bf16x8*)&wp1[oB10];
    bf16x8 C11 = *(const bf16x8*)&wp1[oB10 + oB01];

    #pragma unroll 2
    for (int t = 0; t < NST; ++t) {
        // X(t+1) FIRST (so waiting on it never drains the younger B loads;
        // vmcnt waits drain older ops only). Clamped address on last step.
        const int tx = (t + 1 < NST) ? (t + 1) : (NST - 1);
        const float* xp = &Xr[tx * 16];
        float4 nxa = xok ? *(const float4*)&xp[0] : z4;
        float4 nxb = xok ? *(const float4*)&xp[4] : z4;

        // B(t+2) into the D set (clamped on edge steps -> reload of step 15,
        // values either unused or identical).
        const int tb = (t + 2 < NST) ? (t + 2) : (NST - 1);
        const unsigned short* wp2 = &WpB[tb * wstep];
        bf16x8 D00 = *(const bf16x8*)&wp2[0];
        bf16x8 D01 = *(const bf16x8*)&wp2[oB01];
        bf16x8 D10 = *(const bf16x8*)&wp2[oB10];
        bf16x8 D11 = *(const bf16x8*)&wp2[oB10 + oB01];

        // stats + hi/lo convert of current X (8 values)
        xs += ((xa.x + xa.y) + (xa.z + xa.w)) + ((xb.x + xb.y) + (xb.z + xb.w));
        xq += ((xa.x*xa.x + xa.y*xa.y) + (xa.z*xa.z + xa.w*xa.w))
            + ((xb.x*xb.x + xb.y*xb.y) + (xb.z*xb.z + xb.w*xb.w));
        bf16x8 Ah, Al;
        Ah[0] = (short)bf16rne(xa.x); Ah[1] = (short)bf16rne(xa.y);
        Ah[2] = (short)bf16rne(xa.z); Ah[3] = (short)bf16rne(xa.w);
        Ah[4] = (short)bf16rne(xb.x); Ah[5] = (short)bf16rne(xb.y);
        Ah[6] = (short)bf16rne(xb.z); Ah[7] = (short)bf16rne(xb.w);
        Al[0] = (short)bf16rne(xa.x - bf16tof((unsigned short)Ah[0]));
        Al[1] = (short)bf16rne(xa.y - bf16tof((unsigned short)Ah[1]));
        Al[2] = (short)bf16rne(xa.z - bf16tof((unsigned short)Ah[2]));
        Al[3] = (short)bf16rne(xa.w - bf16tof((unsigned short)Ah[3]));
        Al[4] = (short)bf16rne(xb.x - bf16tof((unsigned short)Ah[4]));
        Al[5] = (short)bf16rne(xb.y - bf16tof((unsigned short)Ah[5]));
        Al[6] = (short)bf16rne(xb.z - bf16tof((unsigned short)Ah[6]));
        Al[7] = (short)bf16rne(xb.w - bf16tof((unsigned short)Ah[7]));

        acc0 = __builtin_amdgcn_mfma_f32_32x32x16_bf16(Ah, A00, acc0, 0, 0, 0);
        acc1 = __builtin_amdgcn_mfma_f32_32x32x16_bf16(Ah, A10, acc1, 0, 0, 0);
        acc0 = __builtin_amdgcn_mfma_f32_32x32x16_bf16(Ah, A01, acc0, 0, 0, 0);
        acc1 = __builtin_amdgcn_mfma_f32_32x32x16_bf16(Ah, A11, acc1, 0, 0, 0);
        acc0 = __builtin_amdgcn_mfma_f32_32x32x16_bf16(Al, A00, acc0, 0, 0, 0);
        acc1 = __builtin_amdgcn_mfma_f32_32x32x16_bf16(Al, A10, acc1, 0, 0, 0);

        // rotate pipelines
        xa = nxa; xb = nxb;
        A00 = C00; A01 = C01; A10 = C10; A11 = C11;
        C00 = D00; C01 = D01; C10 = D10; C11 = D11;
    }

    // ---- stats: fold kh pair, write wave partials
    xs += __shfl_xor(xs, 32);
    xq += __shfl_xor(xq, 32);
    if (ln < 32) { xsS[s][n] = xs; xqS[s][n] = xq; }

    // ---- write per-wave C partials: red[(s*64 + d)*RSTT + token_row]
    {
        float* rp0 = &red[(s * DBOT + n) * RSTT + 4 * kh];        // tj=0: d=n
        float* rp1 = &red[(s * DBOT + 32 + n) * RSTT + 4 * kh];   // tj=1
        const f32x4 a0 = {acc0[0],  acc0[1],  acc0[2],  acc0[3]};
        const f32x4 a1 = {acc0[4],  acc0[5],  acc0[6],  acc0[7]};
        const f32x4 a2 = {acc0[8],  acc0[9],  acc0[10], acc0[11]};
        const f32x4 a3 = {acc0[12], acc0[13], acc0[14], acc0[15]};
        *(f32x4*)&rp0[0]  = a0;
        *(f32x4*)&rp0[8]  = a1;
        *(f32x4*)&rp0[16] = a2;
        *(f32x4*)&rp0[24] = a3;
        const f32x4 b0 = {acc1[0],  acc1[1],  acc1[2],  acc1[3]};
        const f32x4 b1 = {acc1[4],  acc1[5],  acc1[6],  acc1[7]};
        const f32x4 b2 = {acc1[8],  acc1[9],  acc1[10], acc1[11]};
        const f32x4 b3 = {acc1[12], acc1[13], acc1[14], acc1[15]};
        *(f32x4*)&rp1[0]  = b0;
        *(f32x4*)&rp1[8]  = b1;
        *(f32x4*)&rp1[16] = b2;
        *(f32x4*)&rp1[24] = b3;
    }
    __syncthreads();

    // ---- epilogue: token = tid>>4; 16 threads/token; d = cq + 16*i
    {
        const int tok = tid >> 4;
        const int cq  = tid & 15;
        const float invH = 1.0f / (float)H;
        const float rsum = ((xsS[0][tok] + xsS[1][tok]) + (xsS[2][tok] + xsS[3][tok]))
                         + ((xsS[4][tok] + xsS[5][tok]) + (xsS[6][tok] + xsS[7][tok]));
        const float rsq  = ((xqS[0][tok] + xqS[1][tok]) + (xqS[2][tok] + xqS[3][tok]))
                         + ((xqS[4][tok] + xqS[5][tok]) + (xqS[6][tok] + xqS[7][tok]));
        const float mu   = rsum * invH;
        const float var  = rsq * invH - mu * mu;
        const float rstd = 1.0f / sqrtf(var + 1e-5f);

        float lg[NE];
        #pragma unroll
        for (int e = 0; e < NE; ++e) lg[e] = 0.f;
        #pragma unroll
        for (int i = 0; i < 4; ++i) {
            const int d = cq + 16 * i;
            const float A = (((red[(0*DBOT + d)*RSTT + tok] + red[(1*DBOT + d)*RSTT + tok])
                            + (red[(2*DBOT + d)*RSTT + tok] + red[(3*DBOT + d)*RSTT + tok]))
                           + ((red[(4*DBOT + d)*RSTT + tok] + red[(5*DBOT + d)*RSTT + tok])
                            + (red[(6*DBOT + d)*RSTT + tok] + red[(7*DBOT + d)*RSTT + tok])));
            const float t = rstd * (A - mu * BdS[d]) + CdS[d];
            const float z = t / (1.0f + expf(-t));
            #pragma unroll
            for (int e = 0; e < NE; ++e) lg[e] += z * wuS[e * DBOT + d];
        }
        #pragma unroll
        for (int e = 0; e < NE; ++e) {
            lg[e] += __shfl_xor(lg[e], 1);
            lg[e] += __shfl_xor(lg[e], 2);
            lg[e] += __shfl_xor(lg[e], 4);
            lg[e] += __shfl_xor(lg[e], 8);
        }

        if (cq == 0 && tok0 + tok < ntok) {
            // top-2; strict > keeps lowest index on ties (matches lax.top_k)
            float v1 = -INFINITY, v2 = -INFINITY;
            int i1 = -1, i2 = -1;
            #pragma unroll
            for (int e = 0; e < NE; ++e) {
                const float v = lg[e];
                if (v > v1)      { v2 = v1; i2 = i1; v1 = v; i1 = e; }
                else if (v > v2) { v2 = v;  i2 = e; }
            }
            const float e2  = expf(v2 - v1);
            const float inv = 1.0f / (1.0f + e2);
            float o[NE];
            #pragma unroll
            for (int e = 0; e < NE; ++e)
                o[e] = (e == i1) ? inv : ((e == i2) ? e2 * inv : 0.0f);
            float4* op = (float4*)&out[(tok0 + tok) * NE];
            op[0] = make_float4(o[0], o[1], o[2], o[3]);
            op[1] = make_float4(o[4], o[5], o[6], o[7]);
        }
    }
}

extern "C" void kernel_launch(void* const* d_in, const int* in_sizes, int n_in,
                              void* d_out, int out_size, void* d_ws, size_t ws_size,
                              hipStream_t stream) {
    const float* X     = (const float*)d_in[0];
    const float* Wd    = (const float*)d_in[1];
    const float* Wu    = (const float*)d_in[2];
    const float* gamma = (const float*)d_in[3];
    const float* beta  = (const float*)d_in[4];
    float* out = (float*)d_out;

    unsigned short* Wp = (unsigned short*)d_ws;                 // 512 KB
    float* Bd = (float*)((char*)d_ws + WP_SHORTS * sizeof(short));
    float* Cd = Bd + DBOT;

    const int ntok = in_sizes[0] / H;              // 16384
    const int nblk = (ntok + NTB - 1) / NTB;       // 512

    hipLaunchKernelGGL(prep_kernel, dim3(DBOT), dim3(256), 0, stream,
                       Wd, gamma, beta, Wp, Bd, Cd);
    hipLaunchKernelGGL(router_kernel, dim3(nblk), dim3(512), 0, stream,
                       X, Wp, Wu, Bd, Cd, out, ntok);
}